// Round 3
// baseline (68.953 us; speedup 1.0000x reference)
//
#include <hip/hip_runtime.h>

// Problem: B=4, P=12, H=W=32, K_STEP=12, NUM_CELLS=1024, TE_DEPTH=168, F=1192.
//
// Dtypes (established rounds 0-2): ALL float inputs fp32, TE int32, OUTPUT fp32.
// Evidence: flat absmax was EXACTLY 454.0 in both the zero-output round and the
// bf16-store round => bf16 stores only covered the lower half of an fp32-sized
// buffer (ref max lives in `results` near the end, stayed zero). Per-output err
// 0.837890625 = 0.8984375 - 0.060546875 (Y_ref max minus a packed x value that
// landed in Y's upper words) confirms. Round-1 NaN = fp32 misread as bf16
// (mantissa halves get random bf16 exponents). The test's "bf16" label / k=8
// floor threshold is comparison policy (bf16-rounded ref), not buffer dtype.
//
// Algorithm: one-hot matmuls collapse to row-gather + add:
//   logits[b,p,cell,j]  = W_trans[te_idx(b,p)][j] + W_trans[168+cell][j]
//   restart_logit       = W_restart[te_idx] + W_restart[168+cell]
//   bias_w              = W_bias[te_idx]    + W_bias[168+cell]
// Stencil: cell (h,w) receives channel d of neighbor at offset (dr,dc)_d;
// trans_prob is loop-invariant -> 8 incoming-edge weights cached in registers;
// x grid double-buffered in padded 34x34 LDS (zero border = jnp.pad).
// One block per (b,p) slice, one thread per cell.

namespace {
constexpr int PP  = 12;     // P
constexpr int NC  = 1024;   // 32*32
constexpr int TED = 168;    // TE_DEPTH
constexpr int KS  = 12;     // K_STEP
constexpr int PAD = 34;     // padded grid dim
// flat output offsets (elements), return order:
// Y(4096) | x(49152) | trans(393216) | restart(49152) | results(638976)
constexpr long O_X   = 4096;
constexpr long O_TP  = 53248;
constexpr long O_RP  = 446464;
constexpr long O_RES = 495616;
}

__global__ __launch_bounds__(1024) void rwr_fused(
    const float* __restrict__ X,     // (B,P,32,32,1) fp32
    const int* __restrict__ TE,      // (B,24,2) int32
    const float* __restrict__ Wt,    // (1192,8) fp32
    const float* __restrict__ Wr,    // (1192,1) fp32
    const float* __restrict__ Wb,    // (1192,1) fp32
    float* __restrict__ out)         // fp32
{
    __shared__ float tp[NC * 8];         // trans_prob, 32 KB
    __shared__ float xb0[PAD * PAD];     // padded x grids, double-buffered
    __shared__ float xb1[PAD * PAD];

    const int bp   = blockIdx.x;         // b*12 + p
    const int b    = bp / PP;
    const int p    = bp - b * PP;
    const int cell = threadIdx.x;        // 0..1023
    const int h    = cell >> 5;
    const int w    = cell & 31;

    // zero both padded x buffers (borders stay 0 forever)
    for (int i = threadIdx.x; i < PAD * PAD; i += 1024) { xb0[i] = 0.f; xb1[i] = 0.f; }
    __syncthreads();

    const int te = TE[(b * 24 + p) * 2 + 0] * 24 + TE[(b * 24 + p) * 2 + 1];

    // softmax over 8 logits
    float pr[8];
    float m = -1e30f;
    #pragma unroll
    for (int j = 0; j < 8; ++j) {
        pr[j] = Wt[te * 8 + j] + Wt[(TED + cell) * 8 + j];
        m = fmaxf(m, pr[j]);
    }
    float s = 0.f;
    #pragma unroll
    for (int j = 0; j < 8; ++j) { pr[j] = __expf(pr[j] - m); s += pr[j]; }
    const float inv = 1.f / s;
    #pragma unroll
    for (int j = 0; j < 8; ++j) { pr[j] *= inv; tp[cell * 8 + j] = pr[j]; }

    const float rp    = 1.f / (1.f + __expf(-(Wr[te] + Wr[TED + cell])));
    const float x0    = X[bp * NC + cell];
    const float xbias = (Wb[te] + Wb[TED + cell]) * x0;

    xb0[(h + 1) * PAD + (w + 1)] = x0;
    __syncthreads();   // tp + initial grid visible

    // incoming-edge weights: direction d has offset (dr[d],dc[d]);
    // OOB neighbors read x=0 from the padded border, so weight value is moot.
    const int drr[8] = {-1,-1,-1, 0, 0, 1, 1, 1};
    const int dcc[8] = {-1, 0, 1,-1, 1,-1, 0, 1};
    float wn[8];
    #pragma unroll
    for (int d = 0; d < 8; ++d) {
        const int nh = h + drr[d], nw = w + dcc[d];
        const bool ok = ((unsigned)nh < 32u) && ((unsigned)nw < 32u);
        const int nidx = ok ? (nh * 32 + nw) : 0;    // clamp to avoid OOB LDS read
        wn[d] = tp[nidx * 8 + d];
    }

    float res[KS + 1];
    res[0] = x0;
    float x = x0;
    float* cur = xb0;
    float* nxt = xb1;
    #pragma unroll
    for (int k = 0; k < KS; ++k) {
        float xt = 0.f;
        #pragma unroll
        for (int d = 0; d < 8; ++d)
            xt += wn[d] * cur[(h + 1 + drr[d]) * PAD + (w + 1 + dcc[d])];
        x = (1.f - rp) * xt + rp * x + xbias;
        res[k + 1] = x;
        nxt[(h + 1) * PAD + (w + 1)] = x;
        float* t = cur; cur = nxt; nxt = t;
        __syncthreads();
    }

    // ---- epilogue: write all 5 outputs (fp32) ----
    const long gci = (long)bp * NC + cell;
    out[O_X + gci] = x;
    #pragma unroll
    for (int j = 0; j < 8; ++j) out[O_TP + gci * 8 + j] = pr[j];
    out[O_RP + gci] = rp;
    #pragma unroll
    for (int k = 0; k <= KS; ++k) out[O_RES + gci * 13 + k] = res[k];
    if (p == PP - 1) out[(long)b * NC + cell] = x;   // Y = x[:, -1]
}

extern "C" void kernel_launch(void* const* d_in, const int* in_sizes, int n_in,
                              void* d_out, int out_size, void* d_ws, size_t ws_size,
                              hipStream_t stream) {
    const float* X  = (const float*)d_in[0];
    const int*   TE = (const int*)d_in[1];
    const float* Wt = (const float*)d_in[2];
    const float* Wr = (const float*)d_in[3];
    const float* Wb = (const float*)d_in[4];
    float* out = (float*)d_out;

    rwr_fused<<<dim3(4 * PP), dim3(1024), 0, stream>>>(X, TE, Wt, Wr, Wb, out);
}